// Round 1
// baseline (20125.832 us; speedup 1.0000x reference)
//
#include <hip/hip_runtime.h>

#define T_STEPS 512
#define NB 64
#define D_IN 1024
#define HID 1024
#define G4 4096
#define KTOT 2048

typedef short short8 __attribute__((ext_vector_type(8)));
typedef float f32x4 __attribute__((ext_vector_type(4)));

static __device__ __forceinline__ unsigned short f2bf(float f) {
    unsigned int u = __builtin_bit_cast(unsigned int, f);
    u += 0x7fffu + ((u >> 16) & 1u);
    return (unsigned short)(u >> 16);
}

// Build Wc bf16 [4096][2048]: cols 0..1023 = W_ih row, 1024..2047 = W_hh row.
__global__ void cvt_w_kernel(const float* __restrict__ wih, const float* __restrict__ whh,
                             unsigned short* __restrict__ wc) {
    size_t idx = ((size_t)blockIdx.x * blockDim.x + threadIdx.x) * 8;
    if (idx >= (size_t)G4 * KTOT) return;
    int k = (int)(idx & (KTOT - 1));
    int g = (int)(idx >> 11);
    const float* src = (k < D_IN) ? (wih + (size_t)g * D_IN + k)
                                  : (whh + (size_t)g * HID + (k - D_IN));
    float4 a = *(const float4*)src;
    float4 b = *(const float4*)(src + 4);
    short8 v;
    v[0] = (short)f2bf(a.x); v[1] = (short)f2bf(a.y);
    v[2] = (short)f2bf(a.z); v[3] = (short)f2bf(a.w);
    v[4] = (short)f2bf(b.x); v[5] = (short)f2bf(b.y);
    v[6] = (short)f2bf(b.z); v[7] = (short)f2bf(b.w);
    *(short8*)(wc + idx) = v;
}

// x (N,T,D) fp32 -> xb (T,N,D) bf16
__global__ void cvt_x_kernel(const float* __restrict__ x, unsigned short* __restrict__ xb) {
    size_t idx = ((size_t)blockIdx.x * blockDim.x + threadIdx.x) * 8;
    if (idx >= (size_t)NB * T_STEPS * D_IN) return;
    int d = (int)(idx & (D_IN - 1));
    size_t nt = idx >> 10;           // n*512 + t
    int t = (int)(nt & (T_STEPS - 1));
    int n = (int)(nt >> 9);
    float4 a = *(const float4*)(x + idx);
    float4 b = *(const float4*)(x + idx + 4);
    short8 v;
    v[0] = (short)f2bf(a.x); v[1] = (short)f2bf(a.y);
    v[2] = (short)f2bf(a.z); v[3] = (short)f2bf(a.w);
    v[4] = (short)f2bf(b.x); v[5] = (short)f2bf(b.y);
    v[6] = (short)f2bf(b.z); v[7] = (short)f2bf(b.w);
    *(short8*)(xb + (((size_t)t * NB + n) << 10) + d) = v;
}

__global__ void init_kernel(unsigned short* __restrict__ h0, float* __restrict__ c,
                            const float* __restrict__ bih, const float* __restrict__ bhh,
                            float* __restrict__ bias) {
    int i = blockIdx.x * blockDim.x + threadIdx.x;
    if (i < NB * HID) { h0[i] = 0; c[i] = 0.f; }
    if (i < G4) bias[i] = bih[i] + bhh[i];
}

// One timestep: gates = [x_t, h] @ Wc^T + bias; pointwise; write y, h_out, c.
// grid = 64 WGs (WG wg owns hidden units [wg*16, wg*16+16)), 256 threads = 4 waves.
// Wave w computes gate-type w's 16 columns via mfma_f32_16x16x32_bf16.
__global__ __launch_bounds__(256) void lstm_step_kernel(
    const unsigned short* __restrict__ xt,    // [64][1024] bf16
    const unsigned short* __restrict__ h_in,  // [64][1024] bf16
    unsigned short* __restrict__ h_out,       // [64][1024] bf16
    const unsigned short* __restrict__ wc,    // [4096][2048] bf16
    const float* __restrict__ bias,           // [4096]
    float* __restrict__ c,                    // [64][1024]
    float* __restrict__ yt) {                 // d_out + t*HID
    __shared__ float sh[4][NB][16];
    const int tid = threadIdx.x;
    const int wave = tid >> 6;
    const int lane = tid & 63;
    const int lrow = lane & 15;   // A row offset / B col / C col
    const int kgrp = lane >> 4;   // k-group
    const int wg = blockIdx.x;
    const int gcol = wave * HID + wg * 16 + lrow;

    const unsigned short* wp = wc + (size_t)gcol * KTOT + kgrp * 8;
    const unsigned short* ax = xt + lrow * D_IN + kgrp * 8;
    const unsigned short* ah = h_in + lrow * HID + kgrp * 8;

    f32x4 acc0 = {0.f,0.f,0.f,0.f}, acc1 = {0.f,0.f,0.f,0.f};
    f32x4 acc2 = {0.f,0.f,0.f,0.f}, acc3 = {0.f,0.f,0.f,0.f};

    #pragma unroll 8
    for (int kb = 0; kb < 32; ++kb) {   // K over x: 1024
        short8 b  = *(const short8*)(wp + kb * 32);
        short8 a0 = *(const short8*)(ax + kb * 32);
        short8 a1 = *(const short8*)(ax + 16 * D_IN + kb * 32);
        short8 a2 = *(const short8*)(ax + 32 * D_IN + kb * 32);
        short8 a3 = *(const short8*)(ax + 48 * D_IN + kb * 32);
        acc0 = __builtin_amdgcn_mfma_f32_16x16x32_bf16(a0, b, acc0, 0, 0, 0);
        acc1 = __builtin_amdgcn_mfma_f32_16x16x32_bf16(a1, b, acc1, 0, 0, 0);
        acc2 = __builtin_amdgcn_mfma_f32_16x16x32_bf16(a2, b, acc2, 0, 0, 0);
        acc3 = __builtin_amdgcn_mfma_f32_16x16x32_bf16(a3, b, acc3, 0, 0, 0);
    }
    #pragma unroll 8
    for (int kb = 0; kb < 32; ++kb) {   // K over h: 1024
        short8 b  = *(const short8*)(wp + D_IN + kb * 32);
        short8 a0 = *(const short8*)(ah + kb * 32);
        short8 a1 = *(const short8*)(ah + 16 * HID + kb * 32);
        short8 a2 = *(const short8*)(ah + 32 * HID + kb * 32);
        short8 a3 = *(const short8*)(ah + 48 * HID + kb * 32);
        acc0 = __builtin_amdgcn_mfma_f32_16x16x32_bf16(a0, b, acc0, 0, 0, 0);
        acc1 = __builtin_amdgcn_mfma_f32_16x16x32_bf16(a1, b, acc1, 0, 0, 0);
        acc2 = __builtin_amdgcn_mfma_f32_16x16x32_bf16(a2, b, acc2, 0, 0, 0);
        acc3 = __builtin_amdgcn_mfma_f32_16x16x32_bf16(a3, b, acc3, 0, 0, 0);
    }

    const float bv = bias[gcol];
    // C/D layout: col = lane&15, row = (lane>>4)*4 + r   [m89-verified]
    #pragma unroll
    for (int r = 0; r < 4; ++r) {
        sh[wave][ 0 + kgrp * 4 + r][lrow] = acc0[r] + bv;
        sh[wave][16 + kgrp * 4 + r][lrow] = acc1[r] + bv;
        sh[wave][32 + kgrp * 4 + r][lrow] = acc2[r] + bv;
        sh[wave][48 + kgrp * 4 + r][lrow] = acc3[r] + bv;
    }
    __syncthreads();

    #pragma unroll
    for (int p = tid; p < NB * 16; p += 256) {
        int n = p >> 4, jj = p & 15;
        float iv = sh[0][n][jj], fv = sh[1][n][jj], gv = sh[2][n][jj], ov = sh[3][n][jj];
        iv = 1.f / (1.f + __expf(-iv));
        fv = 1.f / (1.f + __expf(-fv));
        ov = 1.f / (1.f + __expf(-ov));
        float eg = __expf(2.f * gv);
        gv = 1.f - 2.f / (eg + 1.f);          // tanh, saturates cleanly
        int j = wg * 16 + jj;
        float cc = fv * c[(size_t)n * HID + j] + iv * gv;
        c[(size_t)n * HID + j] = cc;
        float ec = __expf(2.f * cc);
        float th = 1.f - 2.f / (ec + 1.f);
        float hh = ov * th;
        yt[(size_t)n * (T_STEPS * HID) + j] = hh;   // y[n][t][j]
        h_out[(size_t)n * HID + j] = (unsigned short)f2bf(hh);
    }
}

extern "C" void kernel_launch(void* const* d_in, const int* in_sizes, int n_in,
                              void* d_out, int out_size, void* d_ws, size_t ws_size,
                              hipStream_t stream) {
    const float* x   = (const float*)d_in[0];
    const float* wih = (const float*)d_in[1];
    const float* whh = (const float*)d_in[2];
    const float* bih = (const float*)d_in[3];
    const float* bhh = (const float*)d_in[4];
    float* y = (float*)d_out;

    char* ws = (char*)d_ws;
    // layout: Wc 16MiB | xb 64MiB | bias 64KiB | c 256KiB | h0 128KiB | h1 128KiB
    unsigned short* Wc = (unsigned short*)ws;
    unsigned short* xb = (unsigned short*)(ws + ((size_t)16 << 20));
    float* bias        = (float*)(ws + ((size_t)80 << 20));
    float* c           = (float*)(ws + ((size_t)80 << 20) + (1u << 16));
    unsigned short* h0 = (unsigned short*)(ws + ((size_t)80 << 20) + (1u << 16) + (1u << 18));
    unsigned short* h1 = h0 + NB * HID;
    if (ws_size < ((size_t)81 << 20)) return;  // scratch too small: no-op (diagnosable via absmax == ref max)

    hipLaunchKernelGGL(cvt_w_kernel, dim3(4096), dim3(256), 0, stream, wih, whh, Wc);
    hipLaunchKernelGGL(cvt_x_kernel, dim3(16384), dim3(256), 0, stream, x, xb);
    hipLaunchKernelGGL(init_kernel, dim3(256), dim3(256), 0, stream, h0, c, bih, bhh, bias);

    for (int t = 0; t < T_STEPS; ++t) {
        const unsigned short* hi = (t & 1) ? h1 : h0;
        unsigned short* ho       = (t & 1) ? h0 : h1;
        hipLaunchKernelGGL(lstm_step_kernel, dim3(64), dim3(256), 0, stream,
                           xb + (size_t)t * (NB * D_IN), hi, ho, Wc, bias, c,
                           y + (size_t)t * HID);
    }
}